// Round 17
// baseline (233.845 us; speedup 1.0000x reference)
//
#include <hip/hip_runtime.h>
#include <math.h>

#define B_ 8
#define T_ 64
#define N_ 196
#define D_ 768
#define K_ 8
#define FEAT 40
#define EPSF 1e-6f

constexpr int BN = B_ * N_;                        // 1568
constexpr int ROWS = B_ * T_ * N_;                 // 100352
constexpr long long HSIZE = (long long)ROWS * D_;  // 77070336
constexpr int WPR = D_ / 2;                        // 384 words per row
constexpr unsigned RSTRIDE2 = (unsigned)N_ * WPR;  // float2 stride t -> t+1
constexpr int NBLK = 224;                          // 224 * 7 = 1568 exactly
constexpr int CPB  = 7;

typedef float v2f __attribute__((ext_vector_type(2)));

__device__ __forceinline__ float wredux(float v) {
#pragma unroll
    for (int off = 32; off > 0; off >>= 1)
        v += __shfl_xor(v, off, 64);
    return v;
}

// round-to-nearest-even f32 pair -> packed bf16x2
__device__ __forceinline__ unsigned pack_bf16(float f0, float f1) {
    unsigned a = __float_as_uint(f0);
    unsigned b = __float_as_uint(f1);
    a = (a + 0x7fffu + ((a >> 16) & 1u)) >> 16;
    b = (b + 0x7fffu + ((b >> 16) & 1u)) & 0xffff0000u;
    return a | b;
}
__device__ __forceinline__ float bf_lo(unsigned u) { return __uint_as_float(u << 16); }
__device__ __forceinline__ float bf_hi(unsigned u) { return __uint_as_float(u & 0xffff0000u); }

// W = softplus(W_raw) -> d_out tail;  beta_s = sigmoid(beta) -> ws
__global__ __launch_bounds__(256) void k_wsp(const float* __restrict__ wraw,
                                             const float* __restrict__ beta,
                                             float* __restrict__ wout,
                                             float* __restrict__ beta_s) {
    int i = blockIdx.x * blockDim.x + threadIdx.x;
    if (i < FEAT * D_) {
        float xw = wraw[i];
        wout[i] = fmaxf(xw, 0.0f) + log1pf(expf(-fabsf(xw)));
    }
    if (i < D_) beta_s[i] = 1.0f / (1.0f + expf(-beta[i]));
}

// Persistent: 224 blocks x 7 columns each (1 block/CU, 16 waves).
// Per column, ONE fused memory phase: D(prev col: LDS bf16 -> h nt-store)
// interleaved with A1(cur col: x load -> pack -> LDS), so the HBM read and
// write streams run simultaneously (round-16 limiter: serialized phases on
// 1 block/CU left each direction idle). x crosses HBM once, h once: 2-stream.
__global__ __launch_bounds__(1024)
void k_persist(const float* __restrict__ x,
               const float* __restrict__ mask,
               const float* __restrict__ pw,
               const float* __restrict__ wsp,
               const float* __restrict__ beta_s,
               float* __restrict__ h) {
    __shared__ unsigned xb[T_][WPR];      // 96 KB: x column as bf16x2
    __shared__ float vpart[T_][K_ + 1];
    __shared__ float sf[FEAT];
    __shared__ float ylds[D_];
    __shared__ float sm[2][T_];           // mask ping-pong (cur = ci&1)

    const int tid  = threadIdx.x;
    const int lane = tid & 63;
    const int w    = tid >> 6;            // 0..15
    const v2f* x2 = (const v2f*)x;
    v2f* h2 = (v2f*)h;

    int pb = 0, pn = 0;                   // prev column coords

#pragma unroll 1
    for (int ci = 0; ci < CPB; ++ci) {
        const int col = blockIdx.x + NBLK * ci;
        const int b   = col / N_;
        const int n   = col - b * N_;
        const int cur = ci & 1, prv = cur ^ 1;

        if (tid < T_) sm[cur][tid] = mask[(b * T_ + tid) * N_ + n];

        // y for prev column (from ylds, written by C(ci-1))
        v2f y[6];
        if (ci > 0) {
            const v2f* y2 = (const v2f*)ylds;
#pragma unroll
            for (int c = 0; c < 6; ++c) y[c] = y2[c * 64 + lane];
        }

        // ---- M: fused D(prev) + A1(cur); wave w owns rows 4w..4w+3 ----
        unsigned qcur = (unsigned)((b * T_ + 4 * w) * N_ + n) * WPR;
        unsigned qprv = (unsigned)((pb * T_ + 4 * w) * N_ + pn) * WPR;
#pragma unroll
        for (int chunk = 0; chunk < 2; ++chunk) {
            const int r0 = 4 * w + 2 * chunk;
            // (1) issue current column's loads (12 in flight)
            v2f xv[2][6];
#pragma unroll
            for (int rr = 0; rr < 2; ++rr)
#pragma unroll
                for (int c = 0; c < 6; ++c)
                    xv[rr][c] = x2[qcur + (unsigned)rr * RSTRIDE2 + (unsigned)c * 64 + lane];
            // (2) prev column h from LDS (hides load latency)
            if (ci > 0) {
#pragma unroll
                for (int rr = 0; rr < 2; ++rr) {
                    const float m = sm[prv][r0 + rr];
#pragma unroll
                    for (int c = 0; c < 6; ++c) {
                        unsigned wd = xb[r0 + rr][c * 64 + lane];
                        v2f o;
                        o.x = bf_lo(wd) + m * y[c].x;
                        o.y = bf_hi(wd) + m * y[c].y;
                        __builtin_nontemporal_store(
                            o, h2 + qprv + (unsigned)rr * RSTRIDE2 + (unsigned)c * 64 + lane);
                    }
                }
            }
            // (3) pack current rows into LDS (overwrites rows just consumed)
#pragma unroll
            for (int rr = 0; rr < 2; ++rr)
#pragma unroll
                for (int c = 0; c < 6; ++c)
                    xb[r0 + rr][c * 64 + lane] = pack_bf16(xv[rr][c].x, xv[rr][c].y);
            qcur += 2 * RSTRIDE2;
            qprv += 2 * RSTRIDE2;
        }
        __syncthreads();

        // ---- A2: wave w: k = w&7, rows (w>>3)*32..+32, 2 rows/iter ----
        {
            const int k  = w & 7;
            const int t0 = (w >> 3) * 32;
            v2f u[6];
            const v2f* pw2 = (const v2f*)(pw + k * D_);
#pragma unroll
            for (int c = 0; c < 6; ++c) u[c] = pw2[c * 64 + lane];
#pragma unroll 1
            for (int i = 0; i < 16; ++i) {
                const int t = t0 + 2 * i;
                float a0 = 0.f, a1 = 0.f;
#pragma unroll
                for (int c = 0; c < 6; ++c) {
                    unsigned w0 = xb[t][c * 64 + lane];
                    unsigned w1 = xb[t + 1][c * 64 + lane];
                    a0 += bf_lo(w0) * u[c].x + bf_hi(w0) * u[c].y;
                    a1 += bf_lo(w1) * u[c].x + bf_hi(w1) * u[c].y;
                }
                a0 += __shfl_xor(a0, 1, 64);
                a1 += __shfl_xor(a1, 1, 64);
                float val = (lane & 1) ? a1 : a0;
                val += __shfl_xor(val, 2, 64);
                val += __shfl_xor(val, 4, 64);
                val += __shfl_xor(val, 8, 64);
                val += __shfl_xor(val, 16, 64);
                val += __shfl_xor(val, 32, 64);
                if (lane < 2) vpart[t + lane][k] = val;
            }
        }
        __syncthreads();

        // ---- B: waves 0..7 own k=w; lane = t (validated math) ----
        if (w < K_) {
            const int k = w;
            float v = vpart[lane][k] * sm[cur][lane];
            float s2  = wredux(v * v);
            float rms = sqrtf(s2 * (1.0f / T_) + EPSF);
            float vb  = 2.5f * tanhf(v / (rms + EPSF));
            const float PI = 3.14159265358979323846f;
            float ph = PI * ((float)lane + 0.5f) / (float)T_;
            float c1 = cosf(ph), c2 = cosf(2.0f * ph);
            float n1 = wredux(c1 * c1), n2 = wredux(c2 * c2);
            float S1 = wredux(vb), Sc1 = wredux(vb * c1);
            float Sc2 = wredux(vb * c2), Sq = wredux(vb * vb);
            if (lane == 0) {
                float* o = sf + k * 5;
                o[0] = S1 / (8.0f + EPSF);
                o[1] = Sc1 / (sqrtf(n1) + EPSF);
                o[2] = Sc2 / (sqrtf(n2) + EPSF);
                o[3] = S1 * (1.0f / T_);
                o[4] = sqrtf(Sq * (1.0f / T_) + EPSF);
            }
        }
        __syncthreads();

        // ---- C: ylds[d] = beta_s[d] * sum_f sf[f]*wsp[f][d] ----
        if (tid < D_) {
            float a0 = 0.f, a1 = 0.f;
#pragma unroll
            for (int f = 0; f < FEAT; f += 2) {
                a0 += sf[f]     * wsp[f * D_ + tid];
                a1 += sf[f + 1] * wsp[(f + 1) * D_ + tid];
            }
            ylds[tid] = (a0 + a1) * beta_s[tid];
        }
        __syncthreads();

        pb = b; pn = n;
    }

    // ---- final D for the last column (xb, ylds, sm[(CPB-1)&1] all live) ----
    {
        const int prv = (CPB - 1) & 1;
        v2f y[6];
        const v2f* y2 = (const v2f*)ylds;
#pragma unroll
        for (int c = 0; c < 6; ++c) y[c] = y2[c * 64 + lane];
        unsigned q = (unsigned)((pb * T_ + 4 * w) * N_ + pn) * WPR;
#pragma unroll
        for (int r = 0; r < 4; ++r) {
            const float m = sm[prv][4 * w + r];
#pragma unroll
            for (int c = 0; c < 6; ++c) {
                unsigned wd = xb[4 * w + r][c * 64 + lane];
                v2f o;
                o.x = bf_lo(wd) + m * y[c].x;
                o.y = bf_hi(wd) + m * y[c].y;
                __builtin_nontemporal_store(o, h2 + q + (unsigned)c * 64 + lane);
            }
            q += RSTRIDE2;
        }
    }
}

extern "C" void kernel_launch(void* const* d_in, const int* in_sizes, int n_in,
                              void* d_out, int out_size, void* d_ws, size_t ws_size,
                              hipStream_t stream) {
    const float* x    = (const float*)d_in[0];
    const float* mask = (const float*)d_in[1];
    const float* pw   = (const float*)d_in[2];
    const float* wraw = (const float*)d_in[3];
    const float* beta = (const float*)d_in[4];

    float* h    = (float*)d_out;
    float* wout = h + HSIZE;
    float* beta_s = (float*)d_ws;   // [768]

    hipLaunchKernelGGL(k_wsp, dim3((FEAT * D_ + 255) / 256), dim3(256), 0, stream,
                       wraw, beta, wout, beta_s);
    hipLaunchKernelGGL(k_persist, dim3(NBLK), dim3(1024), 0, stream,
                       x, mask, pw, wout, beta_s, h);
}

// Round 18
// 205.327 us; speedup vs baseline: 1.1389x; 1.1389x over previous
//
#include <hip/hip_runtime.h>
#include <math.h>

#define B_ 8
#define T_ 64
#define N_ 196
#define D_ 768
#define K_ 8
#define FEAT 40
#define EPSF 1e-6f

constexpr int BN = B_ * N_;                        // 1568
constexpr int ROWS = B_ * T_ * N_;                 // 100352
constexpr long long HSIZE = (long long)ROWS * D_;  // 77070336
constexpr int QPR = D_ / 4;                        // 192 float4 per row
constexpr unsigned RSTRIDE = (unsigned)N_ * QPR;   // 37632 v4f per t-step
constexpr long long QTOT = (long long)ROWS * QPR;  // 19.27M float4s

typedef float v4f __attribute__((ext_vector_type(4)));

__device__ __forceinline__ float wredux(float v) {
#pragma unroll
    for (int off = 32; off > 0; off >>= 1)
        v += __shfl_xor(v, off, 64);
    return v;
}

__device__ __forceinline__ float dot4(v4f a, v4f b) {
    return a.x * b.x + a.y * b.y + a.z * b.z + a.w * b.w;
}

// W = softplus(W_raw) -> d_out tail;  beta_s = sigmoid(beta) -> ws
__global__ __launch_bounds__(256) void k_wsp(const float* __restrict__ wraw,
                                             const float* __restrict__ beta,
                                             float* __restrict__ wout,
                                             float* __restrict__ beta_s) {
    int i = blockIdx.x * blockDim.x + threadIdx.x;
    if (i < FEAT * D_) {
        float xw = wraw[i];
        wout[i] = fmaxf(xw, 0.0f) + log1pf(expf(-fabsf(xw)));
    }
    if (i < D_) beta_s[i] = 1.0f / (1.0f + expf(-beta[i]));
}

// Kernel 1: phases A+B+C of the round-15 kernel (no D). One block per
// (b,n), 4 waves, LDS-staged x tiles (single buffer + reg prefetch),
// k-split dots (2 k's/wave, 24 regs — never remats). Output: y' = beta_s*y
// [BN, D] to workspace (4.8 MB -> L2/L3-hot for k_final).
__global__ __launch_bounds__(256)
void k_proj(const float* __restrict__ x,
            const float* __restrict__ mask,
            const float* __restrict__ pw,
            const float* __restrict__ wsp,
            const float* __restrict__ beta_s,
            float* __restrict__ y_ws) {
    __shared__ v4f   xbuf[4][QPR];        // 12 KB x tile
    __shared__ float vpart[T_][K_ + 1];
    __shared__ float sf[FEAT];
    __shared__ float smask[T_];

    const int tid  = threadIdx.x;
    const int lane = tid & 63;
    const int w    = tid >> 6;
    const int bn   = blockIdx.x;
    const int b    = bn / N_;
    const int n    = bn - b * N_;

    v4f u[2][3];
#pragma unroll
    for (int kk = 0; kk < 2; kk++)
#pragma unroll
        for (int c = 0; c < 3; c++)
            u[kk][c] = *(const v4f*)(pw + (2 * w + kk) * D_ + c * 256 + lane * 4);

    if (tid < T_) smask[tid] = mask[(b * T_ + tid) * N_ + n];

    // ---- Phase A: 16 tiles x 4 rows; wave w stages row w of each tile ----
    const v4f* x4 = (const v4f*)x;
    const unsigned TSTRIDE = 4 * RSTRIDE;
    unsigned q = (unsigned)((b * T_ + w) * N_ + n) * QPR;
    v4f R0 = x4[q + lane], R1 = x4[q + 64 + lane], R2 = x4[q + 128 + lane];
#pragma unroll 1
    for (int tile = 0; tile < 16; ++tile) {
        __syncthreads();
        xbuf[w][lane]       = R0;
        xbuf[w][64 + lane]  = R1;
        xbuf[w][128 + lane] = R2;
        if (tile < 15) {
            q += TSTRIDE;
            R0 = x4[q + lane];
            R1 = x4[q + 64 + lane];
            R2 = x4[q + 128 + lane];
        }
        __syncthreads();
#pragma unroll
        for (int r = 0; r < 4; ++r) {
            v4f c0 = xbuf[r][lane];
            v4f c1 = xbuf[r][64 + lane];
            v4f c2 = xbuf[r][128 + lane];
            float a0 = dot4(c0, u[0][0]) + dot4(c1, u[0][1]) + dot4(c2, u[0][2]);
            float a1 = dot4(c0, u[1][0]) + dot4(c1, u[1][1]) + dot4(c2, u[1][2]);
            a0 += __shfl_xor(a0, 1, 64);
            a1 += __shfl_xor(a1, 1, 64);
            float val = (lane & 1) ? a1 : a0;
            val += __shfl_xor(val, 2, 64);
            val += __shfl_xor(val, 4, 64);
            val += __shfl_xor(val, 8, 64);
            val += __shfl_xor(val, 16, 64);
            val += __shfl_xor(val, 32, 64);
            if (lane < 2) vpart[tile * 4 + r][2 * w + lane] = val;
        }
    }
    __syncthreads();

    // ---- Phase B: wave w owns k = w and k = w+4; lane = t ----
#pragma unroll
    for (int kk = 0; kk < 2; kk++) {
        const int k = w + kk * 4;
        float v = vpart[lane][k] * smask[lane];
        float s2  = wredux(v * v);
        float rms = sqrtf(s2 * (1.0f / T_) + EPSF);
        float vb  = 2.5f * tanhf(v / (rms + EPSF));
        const float PI = 3.14159265358979323846f;
        float ph = PI * ((float)lane + 0.5f) / (float)T_;
        float c1 = cosf(ph), c2 = cosf(2.0f * ph);
        float n1 = wredux(c1 * c1), n2 = wredux(c2 * c2);
        float S1 = wredux(vb), Sc1 = wredux(vb * c1);
        float Sc2 = wredux(vb * c2), Sq = wredux(vb * vb);
        if (lane == 0) {
            float* o = sf + k * 5;
            o[0] = S1 / (8.0f + EPSF);
            o[1] = Sc1 / (sqrtf(n1) + EPSF);
            o[2] = Sc2 / (sqrtf(n2) + EPSF);
            o[3] = S1 * (1.0f / T_);
            o[4] = sqrtf(Sq * (1.0f / T_) + EPSF);
        }
    }
    __syncthreads();

    // ---- Phase C: y'[bn][d] = beta_s[d] * sum_f sf[f]*wsp[f][d] ----
    float* yrow = y_ws + (size_t)bn * D_;
#pragma unroll
    for (int i = 0; i < 3; ++i) {
        const int d = tid + 256 * i;
        float a0 = 0.f, a1 = 0.f;
#pragma unroll
        for (int f = 0; f < FEAT; f += 2) {
            a0 += sf[f]     * wsp[f * D_ + d];
            a1 += sf[f + 1] * wsp[(f + 1) * D_ + d];
        }
        yrow[d] = (a0 + a1) * beta_s[d];
    }
}

// Kernel 2: pure 2-stream: h[q] = x[q] + mask[row] * y'[col(q)].
// No LDS, no barriers, ~24 regs -> full occupancy; nt on both x (dead
// after use) and h (write-once). y' rows are L2/L3-hot (4.8 MB, reused
// 64x each).
__global__ __launch_bounds__(256)
void k_final(const float* __restrict__ x,
             const float* __restrict__ maskv,
             const float* __restrict__ y_ws,
             float* __restrict__ h,
             long long stride) {
    const v4f* x4 = (const v4f*)x;
    const v4f* y4 = (const v4f*)y_ws;
    v4f* h4 = (v4f*)h;

    for (long long qq = (long long)blockIdx.x * blockDim.x + threadIdx.x;
         qq < QTOT; qq += stride) {
        const int row = (int)(qq / QPR);
        const int d4  = (int)(qq - (long long)row * QPR);
        const int b   = row / (T_ * N_);
        const int rem = row - b * (T_ * N_);
        const int n   = rem % N_;

        v4f xv = __builtin_nontemporal_load(x4 + qq);
        float m = maskv[row];
        v4f yv = y4[(size_t)(b * N_ + n) * QPR + d4];
        __builtin_nontemporal_store(xv + m * yv, h4 + qq);
    }
}

extern "C" void kernel_launch(void* const* d_in, const int* in_sizes, int n_in,
                              void* d_out, int out_size, void* d_ws, size_t ws_size,
                              hipStream_t stream) {
    const float* x    = (const float*)d_in[0];
    const float* mask = (const float*)d_in[1];
    const float* pw   = (const float*)d_in[2];
    const float* wraw = (const float*)d_in[3];
    const float* beta = (const float*)d_in[4];

    float* h    = (float*)d_out;
    float* wout = h + HSIZE;

    float* beta_s = (float*)d_ws;         // [768]
    float* y_ws   = (float*)d_ws + 1024;  // [BN*768] = 4.8 MB

    hipLaunchKernelGGL(k_wsp, dim3((FEAT * D_ + 255) / 256), dim3(256), 0, stream,
                       wraw, beta, wout, beta_s);
    hipLaunchKernelGGL(k_proj, dim3(BN), dim3(256), 0, stream,
                       x, mask, pw, wout, beta_s, y_ws);
    const int fblocks = 4096;
    hipLaunchKernelGGL(k_final, dim3(fblocks), dim3(256), 0, stream,
                       x, mask, y_ws, h, (long long)fblocks * 256);
}

// Round 19
// 150.424 us; speedup vs baseline: 1.5546x; 1.3650x over previous
//
#include <hip/hip_runtime.h>
#include <math.h>

#define B_ 8
#define T_ 64
#define N_ 196
#define D_ 768
#define K_ 8
#define FEAT 40
#define EPSF 1e-6f

constexpr int BN = B_ * N_;                        // 1568
constexpr int ROWS = B_ * T_ * N_;                 // 100352
constexpr long long HSIZE = (long long)ROWS * D_;  // 77070336
constexpr int QPR = D_ / 4;                        // 192 float4 per row
constexpr unsigned RSTRIDE = (unsigned)N_ * QPR;   // 37632 v4f per t-step

typedef float v4f __attribute__((ext_vector_type(4)));

__device__ __forceinline__ float wredux(float v) {
#pragma unroll
    for (int off = 32; off > 0; off >>= 1)
        v += __shfl_xor(v, off, 64);
    return v;
}

__device__ __forceinline__ float dot4(v4f a, v4f b) {
    return a.x * b.x + a.y * b.y + a.z * b.z + a.w * b.w;
}

// W = softplus(W_raw) -> d_out tail;  beta_s = sigmoid(beta) -> ws
__global__ __launch_bounds__(256) void k_wsp(const float* __restrict__ wraw,
                                             const float* __restrict__ beta,
                                             float* __restrict__ wout,
                                             float* __restrict__ beta_s) {
    int i = blockIdx.x * blockDim.x + threadIdx.x;
    if (i < FEAT * D_) {
        float xw = wraw[i];
        wout[i] = fmaxf(xw, 0.0f) + log1pf(expf(-fabsf(xw)));
    }
    if (i < D_) beta_s[i] = 1.0f / (1.0f + expf(-beta[i]));
}

// Fused, one block per (b,n), 256 threads = 4 waves. Best-measured config
// (round 15, 151 µs = ~95% of the achievable aggregate vmem ceiling):
// - Phase A: LDS-staged x tiles (single buffer, 12 KB), register prefetch
//   across the barrier; k-split dots (2 k's/wave, u = 24 regs, never remats).
// - Phase D: x reload (L3-hot), nt loads+stores.
// Traffic at floor: FETCH = x once (288 MB), WRITE = h exactly (301 MB),
// VGPR 56, no spill, no bank conflicts. The forced 3-stream (x + x-reload
// + h ≈ 900 MB) at ~6 TB/s aggregate is the roofline; on-chip x retention
// alternatives all regress (rounds 9/13/16/17/18).
__global__ __launch_bounds__(256)
void k_fused(const float* __restrict__ x,
             const float* __restrict__ mask,
             const float* __restrict__ pw,
             const float* __restrict__ wsp,
             const float* __restrict__ beta_s,
             float* __restrict__ h) {
    __shared__ v4f   xbuf[4][QPR];        // 12 KB x tile (single buffer)
    __shared__ float vpart[T_][K_ + 1];   // pad: odd stride, conflict-free
    __shared__ float sf[FEAT];
    __shared__ float ylds[D_];
    __shared__ float smask[T_];

    const int tid  = threadIdx.x;
    const int lane = tid & 63;
    const int w    = tid >> 6;
    const int bn   = blockIdx.x;
    const int b    = bn / N_;
    const int n    = bn - b * N_;

    // u-slice for this wave's two k's: 6 v4f = 24 VGPRs, loop-invariant
    v4f u[2][3];
#pragma unroll
    for (int kk = 0; kk < 2; kk++)
#pragma unroll
        for (int c = 0; c < 3; c++)
            u[kk][c] = *(const v4f*)(pw + (2 * w + kk) * D_ + c * 256 + lane * 4);

    if (tid < T_) smask[tid] = mask[(b * T_ + tid) * N_ + n];

    // ---- Phase A: 16 tiles x 4 rows; wave w stages row w of each tile ----
    const v4f* x4 = (const v4f*)x;
    const unsigned TSTRIDE = 4 * RSTRIDE;
    unsigned q = (unsigned)((b * T_ + w) * N_ + n) * QPR;
    v4f R0 = x4[q + lane], R1 = x4[q + 64 + lane], R2 = x4[q + 128 + lane];
#pragma unroll 1
    for (int tile = 0; tile < 16; ++tile) {
        __syncthreads();   // previous tile's LDS reads done -> safe overwrite
        xbuf[w][lane]       = R0;
        xbuf[w][64 + lane]  = R1;
        xbuf[w][128 + lane] = R2;
        if (tile < 15) {   // issue next tile's loads; land under compute
            q += TSTRIDE;
            R0 = x4[q + lane];
            R1 = x4[q + 64 + lane];
            R2 = x4[q + 128 + lane];
        }
        __syncthreads();   // ds_writes visible
#pragma unroll
        for (int r = 0; r < 4; ++r) {
            v4f c0 = xbuf[r][lane];
            v4f c1 = xbuf[r][64 + lane];
            v4f c2 = xbuf[r][128 + lane];
            float a0 = dot4(c0, u[0][0]) + dot4(c1, u[0][1]) + dot4(c2, u[0][2]);
            float a1 = dot4(c0, u[1][0]) + dot4(c1, u[1][1]) + dot4(c2, u[1][2]);
            a0 += __shfl_xor(a0, 1, 64);
            a1 += __shfl_xor(a1, 1, 64);
            float val = (lane & 1) ? a1 : a0;
            val += __shfl_xor(val, 2, 64);
            val += __shfl_xor(val, 4, 64);
            val += __shfl_xor(val, 8, 64);
            val += __shfl_xor(val, 16, 64);
            val += __shfl_xor(val, 32, 64);
            if (lane < 2) vpart[tile * 4 + r][2 * w + lane] = val;
        }
    }
    __syncthreads();

    // ---- Phase B: wave w owns k = w and k = w+4; lane = t ----
#pragma unroll
    for (int kk = 0; kk < 2; kk++) {
        const int k = w + kk * 4;
        float v = vpart[lane][k] * smask[lane];
        float s2  = wredux(v * v);
        float rms = sqrtf(s2 * (1.0f / T_) + EPSF);
        float vb  = 2.5f * tanhf(v / (rms + EPSF));
        const float PI = 3.14159265358979323846f;
        float ph = PI * ((float)lane + 0.5f) / (float)T_;
        float c1 = cosf(ph), c2 = cosf(2.0f * ph);
        float n1 = wredux(c1 * c1), n2 = wredux(c2 * c2);
        float S1 = wredux(vb), Sc1 = wredux(vb * c1);
        float Sc2 = wredux(vb * c2), Sq = wredux(vb * vb);
        if (lane == 0) {
            float* o = sf + k * 5;
            o[0] = S1 / (8.0f + EPSF);
            o[1] = Sc1 / (sqrtf(n1) + EPSF);
            o[2] = Sc2 / (sqrtf(n2) + EPSF);
            o[3] = S1 * (1.0f / T_);
            o[4] = sqrtf(Sq * (1.0f / T_) + EPSF);
        }
    }
    __syncthreads();

    // ---- Phase C: ylds[d] = beta_s[d] * sum_f sf[f]*wsp[f][d] (L2-hot) ----
    for (int d = tid; d < D_; d += 256) {
        float a0 = 0.f, a1 = 0.f;
#pragma unroll
        for (int f = 0; f < FEAT; f += 2) {
            a0 += sf[f]     * wsp[f * D_ + d];
            a1 += sf[f + 1] * wsp[(f + 1) * D_ + d];
        }
        ylds[d] = (a0 + a1) * beta_s[d];
    }
    __syncthreads();

    // ---- Phase D: rows t = w*16..w*16+15; x reload L3-hot; nt stores ----
    const v4f* y4 = (const v4f*)ylds;
    const v4f y0 = y4[lane], y1 = y4[64 + lane], y2 = y4[128 + lane];
    v4f* h4 = (v4f*)h;
    unsigned qD = (unsigned)((b * T_ + w * 16) * N_ + n) * QPR;
    v4f d0 = __builtin_nontemporal_load(x4 + qD + lane);
    v4f d1 = __builtin_nontemporal_load(x4 + qD + 64 + lane);
    v4f d2 = __builtin_nontemporal_load(x4 + qD + 128 + lane);
#pragma unroll 1
    for (int j = 0; j < 16; j++) {
        v4f c0 = d0, c1 = d1, c2 = d2;
        const unsigned qc = qD;
        if (j < 15) {
            qD += RSTRIDE;
            d0 = __builtin_nontemporal_load(x4 + qD + lane);
            d1 = __builtin_nontemporal_load(x4 + qD + 64 + lane);
            d2 = __builtin_nontemporal_load(x4 + qD + 128 + lane);
        }
        const float m = smask[w * 16 + j];
        __builtin_nontemporal_store(c0 + m * y0, h4 + qc + lane);
        __builtin_nontemporal_store(c1 + m * y1, h4 + qc + 64 + lane);
        __builtin_nontemporal_store(c2 + m * y2, h4 + qc + 128 + lane);
    }
}

extern "C" void kernel_launch(void* const* d_in, const int* in_sizes, int n_in,
                              void* d_out, int out_size, void* d_ws, size_t ws_size,
                              hipStream_t stream) {
    const float* x    = (const float*)d_in[0];
    const float* mask = (const float*)d_in[1];
    const float* pw   = (const float*)d_in[2];
    const float* wraw = (const float*)d_in[3];
    const float* beta = (const float*)d_in[4];

    float* h    = (float*)d_out;
    float* wout = h + HSIZE;
    float* beta_s = (float*)d_ws;   // [768]

    hipLaunchKernelGGL(k_wsp, dim3((FEAT * D_ + 255) / 256), dim3(256), 0, stream,
                       wraw, beta, wout, beta_s);
    hipLaunchKernelGGL(k_fused, dim3(BN), dim3(256), 0, stream,
                       x, mask, pw, wout, beta_s, h);
}